// Round 3
// baseline (2996.031 us; speedup 1.0000x reference)
//
#include <hip/hip_runtime.h>
#include <hip/hip_bf16.h>
#include <stdint.h>

// ---------------------------------------------------------------------------
// EncoderRNN: embedding-gather + bidirectional GRU (T=512,B=256,H=E=256) +
// tanh FC (512->512) + softmax FC (512->10).
//
// Dtype handling: inputs/outputs are fp32 per the reference (round-1 NaN =
// fp32-read-as-bf16 signature; round-2 absmax=max|ref| = bf16-written-into-
// fp32-out signature). detect{} sniffs Whh_f bit patterns and sets flag=1 for
// fp32, so the kernel adapts either way; output dtype follows the flag.
//
// Pipeline (bf16 MFMA, fp32 accumulate/state, fp32 gi):
//   detect   : dtype sniff
//   cvt_seg  : weights/biases -> bf16 copies in ws
//   cvt_emb  : embedding table -> bf16 copy in ws
//   zerok    : zero fp32 h-state
//   gi_gemm  : gi = gather(emb) @ Wih^T per time-chunk (fp32 out, tile-skip)
//   rec_step : persistent-weight GRU recurrence, 32 wgs (2 dir x 16 rowgroups),
//              Whh in 192 VGPRs/lane as MFMA B-frags, h fp32 in registers
//   head1    : hid = tanh(rep @ W1^T + b1)
//   head2    : out = softmax(hid @ W2^T + b2), dtype per flag
// ---------------------------------------------------------------------------

using short8  = __attribute__((ext_vector_type(8))) short;
using float4v = __attribute__((ext_vector_type(4))) float;

// ws layout (bytes)
constexpr size_t OFF_FLAG = 0;
constexpr size_t OFF_HST  = 64;                      // fp32 [2][256][256]
constexpr size_t OFF_REP  = OFF_HST  + 524288;       // bf16 [256][512]
constexpr size_t OFF_HID  = OFF_REP  + 262144;       // bf16 [256][512]
constexpr size_t OFF_WIHF = OFF_HID  + 262144;       // bf16 [768][256]
constexpr size_t OFF_WHHF = OFF_WIHF + 393216;
constexpr size_t OFF_WIHB = OFF_WHHF + 393216;
constexpr size_t OFF_WHHB = OFF_WIHB + 393216;
constexpr size_t OFF_BIHF = OFF_WHHB + 393216;       // bf16 [768]
constexpr size_t OFF_BHHF = OFF_BIHF + 1536;
constexpr size_t OFF_BIHB = OFF_BHHF + 1536;
constexpr size_t OFF_BHHB = OFF_BIHB + 1536;
constexpr size_t OFF_W1   = OFF_BHHB + 1536;         // bf16 [512][512]
constexpr size_t OFF_B1   = OFF_W1   + 524288;       // bf16 [512]
constexpr size_t OFF_W2   = OFF_B1   + 1024;         // bf16 [10][512]
constexpr size_t OFF_B2   = OFF_W2   + 10240;        // bf16 [10]
constexpr size_t OFF_EMB  = OFF_B2   + 64;           // bf16 [50000][256]
constexpr size_t OFF_GI   = OFF_EMB  + 25600000;     // fp32 gi buffers

__device__ inline float asf(unsigned int u) {
  union { unsigned int i; float f; } v; v.i = u; return v.f;
}
__device__ inline float bf2f(unsigned short u) {
  return asf(((unsigned int)u) << 16);
}
__device__ inline unsigned short f2bf(float f) {
  union { float f; unsigned int i; } v; v.f = f;
  unsigned int i = v.i;
  return (unsigned short)((i + 0x7FFFu + ((i >> 16) & 1u)) >> 16);  // RNE
}
__device__ inline float fast_sigmoid(float x) {
  float e = __builtin_amdgcn_exp2f(-1.442695040888963f * x);
  return __builtin_amdgcn_rcpf(1.0f + e);
}
__device__ inline float fast_tanh(float x) {
  float e = __builtin_amdgcn_exp2f(2.885390081777927f * x);
  return 1.0f - 2.0f * __builtin_amdgcn_rcpf(e + 1.0f);
}

// ---------------------------------------------------------------------------
// dtype sniffer: flag=1 iff src is fp32-encoded. Reads 16KB of Whh_f. For
// bf16-packed |x|<=1/16 the low-short exponent field (word bits [14:7]) is
// <= 0x7B for every word; fp32 mantissa bits exceed it w.p. ~0.5/word.
__global__ void detect(const unsigned int* __restrict__ w, int* __restrict__ flag) {
  __shared__ int bad;
  if (threadIdx.x == 0) bad = 0;
  __syncthreads();
  int local = 0;
  for (int i = threadIdx.x; i < 4096; i += 256) {
    const unsigned int x = w[i];
    if (((x >> 7) & 0xFFu) > 0x7Bu) local = 1;
  }
  if (local) atomicOr(&bad, 1);
  __syncthreads();
  if (threadIdx.x == 0) flag[0] = bad ? 1 : 0;
}

struct Ptrs { const void* p[12]; };

// convert the 12 small float tensors into bf16 copies in ws
__global__ __launch_bounds__(256) void cvt_seg(Ptrs ps, char* __restrict__ wsb,
                                               const int* __restrict__ flag) {
  const int cnt[12] = {196608, 196608, 196608, 196608, 768, 768, 768, 768,
                       262144, 512, 5120, 10};
  const int off[12] = {(int)OFF_WIHF, (int)OFF_WHHF, (int)OFF_WIHB, (int)OFF_WHHB,
                       (int)OFF_BIHF, (int)OFF_BHHF, (int)OFF_BIHB, (int)OFF_BHHB,
                       (int)OFF_W1,   (int)OFF_B1,   (int)OFF_W2,   (int)OFF_B2};
  const int seg = blockIdx.y;
  const int n = cnt[seg];
  unsigned short* dst = (unsigned short*)(wsb + off[seg]);
  const int stride = gridDim.x * blockDim.x;
  int i = blockIdx.x * blockDim.x + threadIdx.x;
  if (flag[0]) {
    const float* s = (const float*)ps.p[seg];
    for (; i < n; i += stride) dst[i] = f2bf(s[i]);
  } else {
    const unsigned short* s = (const unsigned short*)ps.p[seg];
    for (; i < n; i += stride) dst[i] = s[i];
  }
}

__global__ __launch_bounds__(256) void cvt_emb(const void* __restrict__ src,
                                               unsigned short* __restrict__ dst,
                                               const int* __restrict__ flag) {
  const int n = 12800000;
  const int stride = gridDim.x * blockDim.x;
  int i = blockIdx.x * blockDim.x + threadIdx.x;
  if (flag[0]) {
    const float* s = (const float*)src;
    for (; i < n; i += stride) dst[i] = f2bf(s[i]);
  } else {
    const unsigned short* s = (const unsigned short*)src;
    for (; i < n; i += stride) dst[i] = s[i];
  }
}

// ---------------------------------------------------------------------------
__global__ void zerok(uint4* __restrict__ p, int n4) {
  int i = blockIdx.x * blockDim.x + threadIdx.x;
  if (i < n4) { uint4 z; z.x = z.y = z.z = z.w = 0u; p[i] = z; }
}

// ---------------------------------------------------------------------------
// gi GEMM for one time-chunk window per direction. fp32 output.
// grid = (6 [N tiles of 128], Tc*2 [t x batch-half], 2 [dir]), block = 512.
// Row (b,t) is consumed iff T-l_b <= t < l_b; lens sorted descending =>
// needed rows at time t are exactly b < min(n1,n2).
__global__ __launch_bounds__(512, 4) void gi_gemm(
    const int* __restrict__ seqs, const int* __restrict__ lens,
    const unsigned short* __restrict__ emb,
    const unsigned short* __restrict__ WihF, const unsigned short* __restrict__ WihB,
    float* __restrict__ giF, float* __restrict__ giB,
    int t0f, int t0b)
{
  const int dir = blockIdx.z;
  const int nblk = blockIdx.x;
  const int tl = blockIdx.y >> 1;
  const int bh = blockIdx.y & 1;
  const int t = (dir ? t0b : t0f) + tl;

  int lo = 0, hi = 256;
  while (lo < hi) { int mid = (lo + hi) >> 1; if (lens[mid] > t) lo = mid + 1; else hi = mid; }
  const int n1 = lo;
  lo = 0; hi = 256;
  const int thr2 = 512 - t;
  while (lo < hi) { int mid = (lo + hi) >> 1; if (lens[mid] >= thr2) lo = mid + 1; else hi = mid; }
  const int n2 = lo;
  const int nneed = n1 < n2 ? n1 : n2;
  if (nneed <= bh * 128) return;  // block-uniform early exit (before barrier)

  const unsigned short* Wih = dir ? WihB : WihF;
  float* gi = dir ? giB : giF;

  __shared__ __attribute__((aligned(16))) short lA[128 * 256];  // 64KB, XOR-swizzled

  const int tid = threadIdx.x;
  {
    const int kb = tid & 31;
    const int m0 = tid >> 5;
#pragma unroll
    for (int it = 0; it < 8; ++it) {
      const int m = it * 16 + m0;
      const int b = bh * 128 + m;
      const int tok = seqs[b * 512 + t];
      const uint4 v = *(const uint4*)(const void*)(emb + (size_t)tok * 256 + kb * 8);
      *(uint4*)(void*)(&lA[m * 256 + ((kb ^ (m & 7)) << 3)]) = v;
    }
  }
  __syncthreads();

  const int w = tid >> 6, lane = tid & 63, q = lane >> 4, n16 = lane & 15;
  const int mrow0 = (w & 3) * 32;
  const int ncol0 = (w >> 2) * 64;

  float4v acc[2][4];
#pragma unroll
  for (int mt = 0; mt < 2; ++mt)
#pragma unroll
    for (int nt = 0; nt < 4; ++nt) { float4v z = {0.f, 0.f, 0.f, 0.f}; acc[mt][nt] = z; }

#pragma unroll
  for (int ks = 0; ks < 8; ++ks) {
    short8 a[2];
#pragma unroll
    for (int mt = 0; mt < 2; ++mt) {
      const int m = mrow0 + mt * 16 + n16;
      const int kb = (ks * 4 + q) ^ (m & 7);
      a[mt] = *(const short8*)(const void*)(&lA[m * 256 + kb * 8]);
    }
#pragma unroll
    for (int nt = 0; nt < 4; ++nt) {
      const int j = nblk * 128 + ncol0 + nt * 16 + n16;
      const short8 bfr = *(const short8*)(const void*)(Wih + (size_t)j * 256 + ks * 32 + q * 8);
#pragma unroll
      for (int mt = 0; mt < 2; ++mt)
        acc[mt][nt] = __builtin_amdgcn_mfma_f32_16x16x32_bf16(a[mt], bfr, acc[mt][nt], 0, 0, 0);
    }
  }

#pragma unroll
  for (int mt = 0; mt < 2; ++mt)
#pragma unroll
    for (int nt = 0; nt < 4; ++nt)
#pragma unroll
      for (int r = 0; r < 4; ++r) {
        const int row = mrow0 + mt * 16 + q * 4 + r;  // C/D: col=lane&15, row=(lane>>4)*4+reg
        const int b = bh * 128 + row;
        const int j = nblk * 128 + ncol0 + nt * 16 + n16;
        gi[((size_t)tl * 256 + b) * 768 + j] = acc[mt][nt][r];
      }
}

// ---------------------------------------------------------------------------
// GRU recurrence, one chunk of Tc steps. grid = 32 (dir*16 + rowgroup), block = 512.
// Whh B-frags in 192 VGPRs/lane; gi read fp32 straight from global (L2/L3).
__global__ __launch_bounds__(512, 2) void rec_step(
    const int* __restrict__ lens,
    const unsigned short* __restrict__ WhhF, const unsigned short* __restrict__ WhhB,
    const unsigned short* __restrict__ bihF, const unsigned short* __restrict__ bhhF,
    const unsigned short* __restrict__ bihB, const unsigned short* __restrict__ bhhB,
    const float* __restrict__ giF, const float* __restrict__ giB,
    float* __restrict__ hstate, unsigned short* __restrict__ rep,
    int t0f, int t0b, int Tc)
{
  const int bid = blockIdx.x;
  const int d = bid >> 4;
  const int g = bid & 15;
  const unsigned short* Whh = d ? WhhB : WhhF;
  const unsigned short* bih = d ? bihB : bihF;
  const unsigned short* bhh = d ? bhhB : bhhF;
  const float* gi = d ? giB : giF;
  const int t0 = d ? t0b : t0f;

  const int tid = threadIdx.x, w = tid >> 6, lane = tid & 63, q = lane >> 4, n16 = lane & 15;

  __shared__ __attribute__((aligned(16))) short hB[16 * 256];  // 8KB swizzled bf16 h

  // wave w owns output columns [32w, 32w+32) for all 3 gates: 192 VGPRs of B-frags
  short8 wf[3][2][8];
#pragma unroll
  for (int gate = 0; gate < 3; ++gate)
#pragma unroll
    for (int cbi = 0; cbi < 2; ++cbi) {
      const int j = gate * 256 + (2 * w + cbi) * 16 + n16;
#pragma unroll
      for (int ks = 0; ks < 8; ++ks)
        wf[gate][cbi][ks] = *(const short8*)(const void*)(Whh + (size_t)j * 256 + ks * 32 + q * 8);
    }

  float cr[2], cz[2], bin_[2], bhn_[2];
#pragma unroll
  for (int cbi = 0; cbi < 2; ++cbi) {
    const int j16 = (2 * w + cbi) * 16 + n16;
    cr[cbi]   = bf2f(bih[j16])       + bf2f(bhh[j16]);
    cz[cbi]   = bf2f(bih[256 + j16]) + bf2f(bhh[256 + j16]);
    bin_[cbi] = bf2f(bih[512 + j16]);
    bhn_[cbi] = bf2f(bhh[512 + j16]);
  }

  int len_[4];
#pragma unroll
  for (int r = 0; r < 4; ++r) len_[r] = lens[g * 16 + q * 4 + r];

  float h[2][4];
#pragma unroll
  for (int cbi = 0; cbi < 2; ++cbi) {
    const int j16 = (2 * w + cbi) * 16 + n16;
#pragma unroll
    for (int r = 0; r < 4; ++r)
      h[cbi][r] = hstate[d * 65536 + (g * 16 + q * 4 + r) * 256 + j16];
  }

#pragma unroll
  for (int cbi = 0; cbi < 2; ++cbi) {
    const int j16 = (2 * w + cbi) * 16 + n16;
    const int kb = j16 >> 3;
#pragma unroll
    for (int r = 0; r < 4; ++r) {
      const int row = q * 4 + r;
      hB[row * 256 + ((kb ^ (row & 7)) << 3) + (j16 & 7)] = (short)f2bf(h[cbi][r]);
    }
  }
  __syncthreads();

  for (int s = 0; s < Tc; ++s) {
    const int tl = d ? (Tc - 1 - s) : s;
    const int t = t0 + tl;
    const float* gsrc = gi + ((size_t)tl * 256 + g * 16) * 768;

    float4v acc[3][2];
#pragma unroll
    for (int gate = 0; gate < 3; ++gate)
#pragma unroll
      for (int cbi = 0; cbi < 2; ++cbi) { float4v z = {0.f, 0.f, 0.f, 0.f}; acc[gate][cbi] = z; }

#pragma unroll
    for (int ks = 0; ks < 8; ++ks) {
      const int m = n16;
      const int kb = (ks * 4 + q) ^ (m & 7);
      const short8 a = *(const short8*)(const void*)(&hB[m * 256 + kb * 8]);
#pragma unroll
      for (int gate = 0; gate < 3; ++gate)
#pragma unroll
        for (int cbi = 0; cbi < 2; ++cbi)
          acc[gate][cbi] = __builtin_amdgcn_mfma_f32_16x16x32_bf16(a, wf[gate][cbi][ks], acc[gate][cbi], 0, 0, 0);
    }
    __syncthreads();  // hB reads done before epilogue rewrites it

#pragma unroll
    for (int cbi = 0; cbi < 2; ++cbi) {
      const int j16 = (2 * w + cbi) * 16 + n16;
      const int kb = j16 >> 3;
#pragma unroll
      for (int r = 0; r < 4; ++r) {
        const int row = q * 4 + r;
        const bool act = (t < len_[r]);
        const bool ug  = (t >= 512 - len_[r]);
        const float gr = ug ? gsrc[row * 768 +       j16] : 0.f;
        const float gz = ug ? gsrc[row * 768 + 256 + j16] : 0.f;
        const float gn = ug ? gsrc[row * 768 + 512 + j16] : 0.f;
        const float rr = fast_sigmoid(gr + cr[cbi] + acc[0][cbi][r]);
        const float zz = fast_sigmoid(gz + cz[cbi] + acc[1][cbi][r]);
        const float nn = fast_tanh(gn + bin_[cbi] + rr * (acc[2][cbi][r] + bhn_[cbi]));
        const float hnew = zz * (h[cbi][r] - nn) + nn;
        h[cbi][r] = act ? hnew : h[cbi][r];
        hB[row * 256 + ((kb ^ (row & 7)) << 3) + (j16 & 7)] = (short)f2bf(h[cbi][r]);
      }
    }
    __syncthreads();  // new hB complete before next step's reads
  }

#pragma unroll
  for (int cbi = 0; cbi < 2; ++cbi) {
    const int j16 = (2 * w + cbi) * 16 + n16;
#pragma unroll
    for (int r = 0; r < 4; ++r) {
      const int b = g * 16 + q * 4 + r;
      hstate[d * 65536 + b * 256 + j16] = h[cbi][r];
      rep[b * 512 + d * 256 + j16] = f2bf(h[cbi][r]);
    }
  }
}

// ---------------------------------------------------------------------------
__global__ __launch_bounds__(256, 4) void head1(
    const unsigned short* __restrict__ rep, const unsigned short* __restrict__ W1,
    const unsigned short* __restrict__ b1, unsigned short* __restrict__ hid)
{
  const int mt = blockIdx.x;
  const int nh = blockIdx.y;
  const int tid = threadIdx.x, w = tid >> 6, lane = tid & 63, q = lane >> 4, n16 = lane & 15;

  float4v acc[4];
#pragma unroll
  for (int nt = 0; nt < 4; ++nt) { float4v z = {0.f, 0.f, 0.f, 0.f}; acc[nt] = z; }

#pragma unroll
  for (int ks = 0; ks < 16; ++ks) {
    const short8 a = *(const short8*)(const void*)(rep + (size_t)(mt * 16 + n16) * 512 + ks * 32 + q * 8);
#pragma unroll
    for (int nt = 0; nt < 4; ++nt) {
      const int n = nh * 256 + w * 64 + nt * 16 + n16;
      const short8 bfr = *(const short8*)(const void*)(W1 + (size_t)n * 512 + ks * 32 + q * 8);
      acc[nt] = __builtin_amdgcn_mfma_f32_16x16x32_bf16(a, bfr, acc[nt], 0, 0, 0);
    }
  }
#pragma unroll
  for (int nt = 0; nt < 4; ++nt)
#pragma unroll
    for (int r = 0; r < 4; ++r) {
      const int row = mt * 16 + q * 4 + r;
      const int col = nh * 256 + w * 64 + nt * 16 + n16;
      hid[row * 512 + col] = f2bf(fast_tanh(acc[nt][r] + bf2f(b1[col])));
    }
}

// ---------------------------------------------------------------------------
// out = softmax(hid @ W2^T + b2). One wave per row. Output dtype follows flag.
__global__ __launch_bounds__(64, 4) void head2(
    const unsigned short* __restrict__ hid, const unsigned short* __restrict__ W2,
    const unsigned short* __restrict__ b2, void* __restrict__ out,
    const int* __restrict__ flag)
{
  const int row = blockIdx.x;
  const int lane = threadIdx.x;
  const uint4 hv = *(const uint4*)(const void*)(hid + (size_t)row * 512 + lane * 8);
  const unsigned int hu[4] = {hv.x, hv.y, hv.z, hv.w};

  float logit[10];
#pragma unroll
  for (int j = 0; j < 10; ++j) {
    const uint4 wv = *(const uint4*)(const void*)(W2 + (size_t)j * 512 + lane * 8);
    const unsigned int wu[4] = {wv.x, wv.y, wv.z, wv.w};
    float s = 0.f;
#pragma unroll
    for (int i = 0; i < 4; ++i) {
      s = fmaf(asf(hu[i] << 16), asf(wu[i] << 16), s);
      s = fmaf(asf(hu[i] & 0xffff0000u), asf(wu[i] & 0xffff0000u), s);
    }
#pragma unroll
    for (int off = 32; off > 0; off >>= 1) s += __shfl_xor(s, off);
    logit[j] = s + bf2f(b2[j]);
  }
  float mx = logit[0];
#pragma unroll
  for (int j = 1; j < 10; ++j) mx = fmaxf(mx, logit[j]);
  float e[10]; float sum = 0.f;
#pragma unroll
  for (int j = 0; j < 10; ++j) { e[j] = __builtin_amdgcn_exp2f(1.442695040888963f * (logit[j] - mx)); sum += e[j]; }
  const float rs = __builtin_amdgcn_rcpf(sum);
  if (lane < 10) {
    float p = e[0];
#pragma unroll
    for (int j = 1; j < 10; ++j) p = (lane == j) ? e[j] : p;
    if (flag[0]) ((float*)out)[row * 10 + lane] = p * rs;
    else         ((unsigned short*)out)[row * 10 + lane] = f2bf(p * rs);
  }
}

// ---------------------------------------------------------------------------
extern "C" void kernel_launch(void* const* d_in, const int* in_sizes, int n_in,
                              void* d_out, int out_size, void* d_ws, size_t ws_size,
                              hipStream_t stream)
{
  (void)in_sizes; (void)n_in; (void)out_size;
  const int* seqs = (const int*)d_in[0];
  const int* lens = (const int*)d_in[1];
  char* ws = (char*)d_ws;

  int* flag = (int*)(ws + OFF_FLAG);
  float* hstate = (float*)(ws + OFF_HST);
  unsigned short* rep  = (unsigned short*)(ws + OFF_REP);
  unsigned short* hid  = (unsigned short*)(ws + OFF_HID);
  unsigned short* WihF = (unsigned short*)(ws + OFF_WIHF);
  unsigned short* WhhF = (unsigned short*)(ws + OFF_WHHF);
  unsigned short* WihB = (unsigned short*)(ws + OFF_WIHB);
  unsigned short* WhhB = (unsigned short*)(ws + OFF_WHHB);
  unsigned short* bihF = (unsigned short*)(ws + OFF_BIHF);
  unsigned short* bhhF = (unsigned short*)(ws + OFF_BHHF);
  unsigned short* bihB = (unsigned short*)(ws + OFF_BIHB);
  unsigned short* bhhB = (unsigned short*)(ws + OFF_BHHB);
  unsigned short* W1C  = (unsigned short*)(ws + OFF_W1);
  unsigned short* b1C  = (unsigned short*)(ws + OFF_B1);
  unsigned short* W2C  = (unsigned short*)(ws + OFF_W2);
  unsigned short* b2C  = (unsigned short*)(ws + OFF_B2);
  unsigned short* embC = (unsigned short*)(ws + OFF_EMB);

  detect<<<1, 256, 0, stream>>>((const unsigned int*)d_in[4], flag);
  Ptrs ps;
  ps.p[0] = d_in[3];  ps.p[1] = d_in[4];  ps.p[2] = d_in[7];  ps.p[3] = d_in[8];
  ps.p[4] = d_in[5];  ps.p[5] = d_in[6];  ps.p[6] = d_in[9];  ps.p[7] = d_in[10];
  ps.p[8] = d_in[11]; ps.p[9] = d_in[12]; ps.p[10] = d_in[13]; ps.p[11] = d_in[14];
  cvt_seg<<<dim3(64, 12), 256, 0, stream>>>(ps, ws, flag);
  cvt_emb<<<2048, 256, 0, stream>>>(d_in[2], embC, flag);

  zerok<<<128, 256, 0, stream>>>((uint4*)hstate, 32768);

  // time-chunk size: fp32 gi needs 2*Tc*786432 bytes after OFF_GI; prefer 32
  // (keeps ws top at ~79MB, same as the round-2 footprint that ran in-bounds)
  int Tc = 1;
  const int cands[6] = {32, 16, 8, 4, 2, 1};
  for (int i = 0; i < 6; ++i) {
    if (OFF_GI + 2ull * (size_t)cands[i] * 786432ull <= ws_size) { Tc = cands[i]; break; }
  }
  float* giF = (float*)(ws + OFF_GI);
  float* giB = giF + (size_t)Tc * 256 * 768;

  const int NC = 512 / Tc;
  for (int c = 0; c < NC; ++c) {
    const int t0f = c * Tc;
    const int t0b = 512 - (c + 1) * Tc;
    gi_gemm<<<dim3(6, Tc * 2, 2), 512, 0, stream>>>(seqs, lens, embC, WihF, WihB, giF, giB, t0f, t0b);
    rec_step<<<32, 512, 0, stream>>>(lens, WhhF, WhhB, bihF, bhhF, bihB, bhhB,
                                     giF, giB, hstate, rep, t0f, t0b, Tc);
  }
  head1<<<dim3(16, 2), 256, 0, stream>>>(rep, W1C, b1C, hid);
  head2<<<256, 64, 0, stream>>>(hid, W2C, b2C, d_out, flag);
}

// Round 4
// 2271.104 us; speedup vs baseline: 1.3192x; 1.3192x over previous
//
#include <hip/hip_runtime.h>
#include <hip/hip_bf16.h>
#include <stdint.h>

// ---------------------------------------------------------------------------
// EncoderRNN: embedding-gather + bidirectional GRU (T=512,B=256,H=E=256) +
// tanh FC (512->512) + softmax FC (512->10).
//
// Dtype: inputs fp32 (adaptive via detect), output dtype follows flag.
// R3 passed at 2996us; R4 attacks rec_step's 4.8us/step (floor 0.78us):
//   - gi prefetched into VGPRs at step top (hides ~600cyc L3 latency)
//   - double-buffered hB -> 1 barrier/step (was 2)
//   - gi_gemm for chunk c+1 fused into rec dispatch for chunk c (idle CUs)
// ---------------------------------------------------------------------------

using short8  = __attribute__((ext_vector_type(8))) short;
using float4v = __attribute__((ext_vector_type(4))) float;

// ws layout (bytes)
constexpr size_t OFF_FLAG = 0;
constexpr size_t OFF_HST  = 64;                      // fp32 [2][256][256]
constexpr size_t OFF_REP  = OFF_HST  + 524288;       // bf16 [256][512]
constexpr size_t OFF_HID  = OFF_REP  + 262144;       // bf16 [256][512]
constexpr size_t OFF_WIHF = OFF_HID  + 262144;       // bf16 [768][256]
constexpr size_t OFF_WHHF = OFF_WIHF + 393216;
constexpr size_t OFF_WIHB = OFF_WHHF + 393216;
constexpr size_t OFF_WHHB = OFF_WIHB + 393216;
constexpr size_t OFF_BIHF = OFF_WHHB + 393216;       // bf16 [768]
constexpr size_t OFF_BHHF = OFF_BIHF + 1536;
constexpr size_t OFF_BIHB = OFF_BHHF + 1536;
constexpr size_t OFF_BHHB = OFF_BIHB + 1536;
constexpr size_t OFF_W1   = OFF_BHHB + 1536;         // bf16 [512][512]
constexpr size_t OFF_B1   = OFF_W1   + 524288;       // bf16 [512]
constexpr size_t OFF_W2   = OFF_B1   + 1024;         // bf16 [10][512]
constexpr size_t OFF_B2   = OFF_W2   + 10240;        // bf16 [10]
constexpr size_t OFF_EMB  = OFF_B2   + 64;           // bf16 [50000][256]
constexpr size_t OFF_GI   = OFF_EMB  + 25600000;     // fp32 gi ping-pong

__device__ inline float asf(unsigned int u) {
  union { unsigned int i; float f; } v; v.i = u; return v.f;
}
__device__ inline float bf2f(unsigned short u) {
  return asf(((unsigned int)u) << 16);
}
__device__ inline unsigned short f2bf(float f) {
  union { float f; unsigned int i; } v; v.f = f;
  unsigned int i = v.i;
  return (unsigned short)((i + 0x7FFFu + ((i >> 16) & 1u)) >> 16);  // RNE
}
__device__ inline float fast_sigmoid(float x) {
  float e = __builtin_amdgcn_exp2f(-1.442695040888963f * x);
  return __builtin_amdgcn_rcpf(1.0f + e);
}
__device__ inline float fast_tanh(float x) {
  float e = __builtin_amdgcn_exp2f(2.885390081777927f * x);
  return 1.0f - 2.0f * __builtin_amdgcn_rcpf(e + 1.0f);
}

// ---------------------------------------------------------------------------
__global__ void detect(const unsigned int* __restrict__ w, int* __restrict__ flag) {
  __shared__ int bad;
  if (threadIdx.x == 0) bad = 0;
  __syncthreads();
  int local = 0;
  for (int i = threadIdx.x; i < 4096; i += 256) {
    const unsigned int x = w[i];
    if (((x >> 7) & 0xFFu) > 0x7Bu) local = 1;
  }
  if (local) atomicOr(&bad, 1);
  __syncthreads();
  if (threadIdx.x == 0) flag[0] = bad ? 1 : 0;
}

struct Ptrs { const void* p[12]; };

__global__ __launch_bounds__(256) void cvt_seg(Ptrs ps, char* __restrict__ wsb,
                                               const int* __restrict__ flag) {
  const int cnt[12] = {196608, 196608, 196608, 196608, 768, 768, 768, 768,
                       262144, 512, 5120, 10};
  const int off[12] = {(int)OFF_WIHF, (int)OFF_WHHF, (int)OFF_WIHB, (int)OFF_WHHB,
                       (int)OFF_BIHF, (int)OFF_BHHF, (int)OFF_BIHB, (int)OFF_BHHB,
                       (int)OFF_W1,   (int)OFF_B1,   (int)OFF_W2,   (int)OFF_B2};
  const int seg = blockIdx.y;
  const int n = cnt[seg];
  unsigned short* dst = (unsigned short*)(wsb + off[seg]);
  const int stride = gridDim.x * blockDim.x;
  int i = blockIdx.x * blockDim.x + threadIdx.x;
  if (flag[0]) {
    const float* s = (const float*)ps.p[seg];
    for (; i < n; i += stride) dst[i] = f2bf(s[i]);
  } else {
    const unsigned short* s = (const unsigned short*)ps.p[seg];
    for (; i < n; i += stride) dst[i] = s[i];
  }
}

__global__ __launch_bounds__(256) void cvt_emb(const void* __restrict__ src,
                                               unsigned short* __restrict__ dst,
                                               const int* __restrict__ flag) {
  const int n = 12800000;
  const int stride = gridDim.x * blockDim.x;
  int i = blockIdx.x * blockDim.x + threadIdx.x;
  if (flag[0]) {
    const float* s = (const float*)src;
    for (; i < n; i += stride) dst[i] = f2bf(s[i]);
  } else {
    const unsigned short* s = (const unsigned short*)src;
    for (; i < n; i += stride) dst[i] = s[i];
  }
}

// ---------------------------------------------------------------------------
__global__ void zerok(uint4* __restrict__ p, int n4) {
  int i = blockIdx.x * blockDim.x + threadIdx.x;
  if (i < n4) { uint4 z; z.x = z.y = z.z = z.w = 0u; p[i] = z; }
}

// ---------------------------------------------------------------------------
// standalone gi GEMM (prologue, chunk 0). fp32 out.
// grid = (6, Tc*2, 2), block = 512.
__global__ __launch_bounds__(512, 4) void gi_gemm(
    const int* __restrict__ seqs, const int* __restrict__ lens,
    const unsigned short* __restrict__ emb,
    const unsigned short* __restrict__ WihF, const unsigned short* __restrict__ WihB,
    float* __restrict__ giF, float* __restrict__ giB,
    int t0f, int t0b)
{
  const int dir = blockIdx.z;
  const int nblk = blockIdx.x;
  const int tl = blockIdx.y >> 1;
  const int bh = blockIdx.y & 1;
  const int t = (dir ? t0b : t0f) + tl;

  int lo = 0, hi = 256;
  while (lo < hi) { int mid = (lo + hi) >> 1; if (lens[mid] > t) lo = mid + 1; else hi = mid; }
  const int n1 = lo;
  lo = 0; hi = 256;
  const int thr2 = 512 - t;
  while (lo < hi) { int mid = (lo + hi) >> 1; if (lens[mid] >= thr2) lo = mid + 1; else hi = mid; }
  const int n2 = lo;
  const int nneed = n1 < n2 ? n1 : n2;
  if (nneed <= bh * 128) return;

  const unsigned short* Wih = dir ? WihB : WihF;
  float* gi = dir ? giB : giF;

  __shared__ __attribute__((aligned(16))) short lA[128 * 256];

  const int tid = threadIdx.x;
  {
    const int kb = tid & 31;
    const int m0 = tid >> 5;
#pragma unroll
    for (int it = 0; it < 8; ++it) {
      const int m = it * 16 + m0;
      const int b = bh * 128 + m;
      const int tok = seqs[b * 512 + t];
      const uint4 v = *(const uint4*)(const void*)(emb + (size_t)tok * 256 + kb * 8);
      *(uint4*)(void*)(&lA[m * 256 + ((kb ^ (m & 7)) << 3)]) = v;
    }
  }
  __syncthreads();

  const int w = tid >> 6, lane = tid & 63, q = lane >> 4, n16 = lane & 15;
  const int mrow0 = (w & 3) * 32;
  const int ncol0 = (w >> 2) * 64;

  float4v acc[2][4];
#pragma unroll
  for (int mt = 0; mt < 2; ++mt)
#pragma unroll
    for (int nt = 0; nt < 4; ++nt) { float4v z = {0.f, 0.f, 0.f, 0.f}; acc[mt][nt] = z; }

#pragma unroll
  for (int ks = 0; ks < 8; ++ks) {
    short8 a[2];
#pragma unroll
    for (int mt = 0; mt < 2; ++mt) {
      const int m = mrow0 + mt * 16 + n16;
      const int kb = (ks * 4 + q) ^ (m & 7);
      a[mt] = *(const short8*)(const void*)(&lA[m * 256 + kb * 8]);
    }
#pragma unroll
    for (int nt = 0; nt < 4; ++nt) {
      const int j = nblk * 128 + ncol0 + nt * 16 + n16;
      const short8 bfr = *(const short8*)(const void*)(Wih + (size_t)j * 256 + ks * 32 + q * 8);
#pragma unroll
      for (int mt = 0; mt < 2; ++mt)
        acc[mt][nt] = __builtin_amdgcn_mfma_f32_16x16x32_bf16(a[mt], bfr, acc[mt][nt], 0, 0, 0);
    }
  }

#pragma unroll
  for (int mt = 0; mt < 2; ++mt)
#pragma unroll
    for (int nt = 0; nt < 4; ++nt)
#pragma unroll
      for (int r = 0; r < 4; ++r) {
        const int row = mrow0 + mt * 16 + q * 4 + r;
        const int b = bh * 128 + row;
        const int j = nblk * 128 + ncol0 + nt * 16 + n16;
        gi[((size_t)tl * 256 + b) * 768 + j] = acc[mt][nt][r];
      }
}

// ---------------------------------------------------------------------------
// Fused: blocks 0..31 = GRU recurrence for chunk c (reads gi_rd);
//        blocks 32..32+24*Tc-1 = gi GEMM for chunk c+1 (writes gi_wr).
// block = 512. Single 64KB LDS arena shared by role.
__global__ __launch_bounds__(512, 2) void fused_step(
    const int* __restrict__ seqs, const int* __restrict__ lens,
    const unsigned short* __restrict__ emb,
    const unsigned short* __restrict__ WihF, const unsigned short* __restrict__ WihB,
    const unsigned short* __restrict__ WhhF, const unsigned short* __restrict__ WhhB,
    const unsigned short* __restrict__ bihF, const unsigned short* __restrict__ bhhF,
    const unsigned short* __restrict__ bihB, const unsigned short* __restrict__ bhhB,
    const float* __restrict__ gi_rd, float* __restrict__ gi_wr,
    float* __restrict__ hstate, unsigned short* __restrict__ rep,
    int t0f_rec, int t0b_rec, int t0f_g, int t0b_g, int Tc, int do_gemm)
{
  __shared__ __attribute__((aligned(16))) char smem[65536];
  const int bid = blockIdx.x;
  const int tid = threadIdx.x, w = tid >> 6, lane = tid & 63, q = lane >> 4, n16 = lane & 15;

  if (bid < 32) {
    // ------------------------- recurrence (chunk c) -------------------------
    const int d = bid >> 4;
    const int g = bid & 15;
    const unsigned short* Whh = d ? WhhB : WhhF;
    const unsigned short* bih = d ? bihB : bihF;
    const unsigned short* bhh = d ? bhhB : bhhF;
    const float* gi = gi_rd + (size_t)d * (size_t)Tc * 196608;
    const int t0 = d ? t0b_rec : t0f_rec;

    short* hB0 = (short*)smem;            // 8KB
    short* hB1 = (short*)(smem + 8192);   // 8KB

    // Whh B-frags: wave w owns cols [32w,32w+32) x 3 gates (192 regs/lane)
    short8 wf[3][2][8];
#pragma unroll
    for (int gate = 0; gate < 3; ++gate)
#pragma unroll
      for (int cbi = 0; cbi < 2; ++cbi) {
        const int j = gate * 256 + (2 * w + cbi) * 16 + n16;
#pragma unroll
        for (int ks = 0; ks < 8; ++ks)
          wf[gate][cbi][ks] = *(const short8*)(const void*)(Whh + (size_t)j * 256 + ks * 32 + q * 8);
      }

    float cr[2], cz[2], bin_[2], bhn_[2];
#pragma unroll
    for (int cbi = 0; cbi < 2; ++cbi) {
      const int j16 = (2 * w + cbi) * 16 + n16;
      cr[cbi]   = bf2f(bih[j16])       + bf2f(bhh[j16]);
      cz[cbi]   = bf2f(bih[256 + j16]) + bf2f(bhh[256 + j16]);
      bin_[cbi] = bf2f(bih[512 + j16]);
      bhn_[cbi] = bf2f(bhh[512 + j16]);
    }

    int len_[4];
#pragma unroll
    for (int r = 0; r < 4; ++r) len_[r] = lens[g * 16 + q * 4 + r];

    float h[2][4];
#pragma unroll
    for (int cbi = 0; cbi < 2; ++cbi) {
      const int j16 = (2 * w + cbi) * 16 + n16;
#pragma unroll
      for (int r = 0; r < 4; ++r)
        h[cbi][r] = hstate[d * 65536 + (g * 16 + q * 4 + r) * 256 + j16];
    }

#pragma unroll
    for (int cbi = 0; cbi < 2; ++cbi) {
      const int j16 = (2 * w + cbi) * 16 + n16;
      const int kb = j16 >> 3;
#pragma unroll
      for (int r = 0; r < 4; ++r) {
        const int row = q * 4 + r;
        hB0[row * 256 + ((kb ^ (row & 7)) << 3) + (j16 & 7)] = (short)f2bf(h[cbi][r]);
      }
    }
    __syncthreads();

    for (int s = 0; s < Tc; ++s) {
      const int tl = d ? (Tc - 1 - s) : s;
      const int t = t0 + tl;
      const float* gsrc = gi + ((size_t)tl * 256 + g * 16) * 768;

      // prefetch gi (unconditional; hidden behind ds_read+MFMA chain)
      float gv[2][4][3];
#pragma unroll
      for (int cbi = 0; cbi < 2; ++cbi) {
        const int j16 = (2 * w + cbi) * 16 + n16;
#pragma unroll
        for (int r = 0; r < 4; ++r) {
          const int row = q * 4 + r;
          gv[cbi][r][0] = gsrc[row * 768 +       j16];
          gv[cbi][r][1] = gsrc[row * 768 + 256 + j16];
          gv[cbi][r][2] = gsrc[row * 768 + 512 + j16];
        }
      }

      const short* hRd = (s & 1) ? hB1 : hB0;
      short* hWr = (s & 1) ? hB0 : hB1;

      float4v acc[3][2];
#pragma unroll
      for (int gate = 0; gate < 3; ++gate)
#pragma unroll
        for (int cbi = 0; cbi < 2; ++cbi) { float4v z = {0.f, 0.f, 0.f, 0.f}; acc[gate][cbi] = z; }

#pragma unroll
      for (int ks = 0; ks < 8; ++ks) {
        const int kb = (ks * 4 + q) ^ (n16 & 7);
        const short8 a = *(const short8*)(const void*)(&hRd[n16 * 256 + kb * 8]);
#pragma unroll
        for (int gate = 0; gate < 3; ++gate)
#pragma unroll
          for (int cbi = 0; cbi < 2; ++cbi)
            acc[gate][cbi] = __builtin_amdgcn_mfma_f32_16x16x32_bf16(a, wf[gate][cbi][ks], acc[gate][cbi], 0, 0, 0);
      }

#pragma unroll
      for (int cbi = 0; cbi < 2; ++cbi) {
        const int j16 = (2 * w + cbi) * 16 + n16;
        const int kb = j16 >> 3;
#pragma unroll
        for (int r = 0; r < 4; ++r) {
          const int row = q * 4 + r;
          const bool act = (t < len_[r]);
          const bool ug  = (t >= 512 - len_[r]);
          const float gr = ug ? gv[cbi][r][0] : 0.f;
          const float gz = ug ? gv[cbi][r][1] : 0.f;
          const float gn = ug ? gv[cbi][r][2] : 0.f;
          const float rr = fast_sigmoid(gr + cr[cbi] + acc[0][cbi][r]);
          const float zz = fast_sigmoid(gz + cz[cbi] + acc[1][cbi][r]);
          const float nn = fast_tanh(gn + bin_[cbi] + rr * (acc[2][cbi][r] + bhn_[cbi]));
          const float hnew = zz * (h[cbi][r] - nn) + nn;
          h[cbi][r] = act ? hnew : h[cbi][r];
          hWr[row * 256 + ((kb ^ (row & 7)) << 3) + (j16 & 7)] = (short)f2bf(h[cbi][r]);
        }
      }
      __syncthreads();  // single barrier/step (hWr = buffer read at step s-1)
    }

#pragma unroll
    for (int cbi = 0; cbi < 2; ++cbi) {
      const int j16 = (2 * w + cbi) * 16 + n16;
#pragma unroll
      for (int r = 0; r < 4; ++r) {
        const int b = g * 16 + q * 4 + r;
        hstate[d * 65536 + b * 256 + j16] = h[cbi][r];
        rep[b * 512 + d * 256 + j16] = f2bf(h[cbi][r]);
      }
    }
    return;
  }

  // ------------------------- gi GEMM (chunk c+1) -------------------------
  if (!do_gemm) return;
  const int g2 = bid - 32;
  const int nblk = g2 % 6;
  const int rest = g2 / 6;
  const int yy = rest % (2 * Tc);
  const int dirg = rest / (2 * Tc);
  const int tl = yy >> 1;
  const int bh = yy & 1;
  const int t = (dirg ? t0b_g : t0f_g) + tl;

  int lo = 0, hi = 256;
  while (lo < hi) { int mid = (lo + hi) >> 1; if (lens[mid] > t) lo = mid + 1; else hi = mid; }
  const int n1 = lo;
  lo = 0; hi = 256;
  const int thr2 = 512 - t;
  while (lo < hi) { int mid = (lo + hi) >> 1; if (lens[mid] >= thr2) lo = mid + 1; else hi = mid; }
  const int n2 = lo;
  const int nneed = n1 < n2 ? n1 : n2;
  if (nneed <= bh * 128) return;

  const unsigned short* Wih = dirg ? WihB : WihF;
  float* gi = gi_wr + (size_t)dirg * (size_t)Tc * 196608;

  short* lA = (short*)smem;  // 64KB

  {
    const int kb = tid & 31;
    const int m0 = tid >> 5;
#pragma unroll
    for (int it = 0; it < 8; ++it) {
      const int m = it * 16 + m0;
      const int b = bh * 128 + m;
      const int tok = seqs[b * 512 + t];
      const uint4 v = *(const uint4*)(const void*)(emb + (size_t)tok * 256 + kb * 8);
      *(uint4*)(void*)(&lA[m * 256 + ((kb ^ (m & 7)) << 3)]) = v;
    }
  }
  __syncthreads();

  const int mrow0 = (w & 3) * 32;
  const int ncol0 = (w >> 2) * 64;

  float4v acc[2][4];
#pragma unroll
  for (int mt = 0; mt < 2; ++mt)
#pragma unroll
    for (int nt = 0; nt < 4; ++nt) { float4v z = {0.f, 0.f, 0.f, 0.f}; acc[mt][nt] = z; }

#pragma unroll
  for (int ks = 0; ks < 8; ++ks) {
    short8 a[2];
#pragma unroll
    for (int mt = 0; mt < 2; ++mt) {
      const int m = mrow0 + mt * 16 + n16;
      const int kb = (ks * 4 + q) ^ (m & 7);
      a[mt] = *(const short8*)(const void*)(&lA[m * 256 + kb * 8]);
    }
#pragma unroll
    for (int nt = 0; nt < 4; ++nt) {
      const int j = nblk * 128 + ncol0 + nt * 16 + n16;
      const short8 bfr = *(const short8*)(const void*)(Wih + (size_t)j * 256 + ks * 32 + q * 8);
#pragma unroll
      for (int mt = 0; mt < 2; ++mt)
        acc[mt][nt] = __builtin_amdgcn_mfma_f32_16x16x32_bf16(a[mt], bfr, acc[mt][nt], 0, 0, 0);
    }
  }

#pragma unroll
  for (int mt = 0; mt < 2; ++mt)
#pragma unroll
    for (int nt = 0; nt < 4; ++nt)
#pragma unroll
      for (int r = 0; r < 4; ++r) {
        const int row = mrow0 + mt * 16 + q * 4 + r;
        const int b = bh * 128 + row;
        const int j = nblk * 128 + ncol0 + nt * 16 + n16;
        gi[((size_t)tl * 256 + b) * 768 + j] = acc[mt][nt][r];
      }
}

// ---------------------------------------------------------------------------
__global__ __launch_bounds__(256, 4) void head1(
    const unsigned short* __restrict__ rep, const unsigned short* __restrict__ W1,
    const unsigned short* __restrict__ b1, unsigned short* __restrict__ hid)
{
  const int mt = blockIdx.x;
  const int nh = blockIdx.y;
  const int tid = threadIdx.x, w = tid >> 6, lane = tid & 63, q = lane >> 4, n16 = lane & 15;

  float4v acc[4];
#pragma unroll
  for (int nt = 0; nt < 4; ++nt) { float4v z = {0.f, 0.f, 0.f, 0.f}; acc[nt] = z; }

#pragma unroll
  for (int ks = 0; ks < 16; ++ks) {
    const short8 a = *(const short8*)(const void*)(rep + (size_t)(mt * 16 + n16) * 512 + ks * 32 + q * 8);
#pragma unroll
    for (int nt = 0; nt < 4; ++nt) {
      const int n = nh * 256 + w * 64 + nt * 16 + n16;
      const short8 bfr = *(const short8*)(const void*)(W1 + (size_t)n * 512 + ks * 32 + q * 8);
      acc[nt] = __builtin_amdgcn_mfma_f32_16x16x32_bf16(a, bfr, acc[nt], 0, 0, 0);
    }
  }
#pragma unroll
  for (int nt = 0; nt < 4; ++nt)
#pragma unroll
    for (int r = 0; r < 4; ++r) {
      const int row = mt * 16 + q * 4 + r;
      const int col = nh * 256 + w * 64 + nt * 16 + n16;
      hid[row * 512 + col] = f2bf(fast_tanh(acc[nt][r] + bf2f(b1[col])));
    }
}

// ---------------------------------------------------------------------------
__global__ __launch_bounds__(64, 4) void head2(
    const unsigned short* __restrict__ hid, const unsigned short* __restrict__ W2,
    const unsigned short* __restrict__ b2, void* __restrict__ out,
    const int* __restrict__ flag)
{
  const int row = blockIdx.x;
  const int lane = threadIdx.x;
  const uint4 hv = *(const uint4*)(const void*)(hid + (size_t)row * 512 + lane * 8);
  const unsigned int hu[4] = {hv.x, hv.y, hv.z, hv.w};

  float logit[10];
#pragma unroll
  for (int j = 0; j < 10; ++j) {
    const uint4 wv = *(const uint4*)(const void*)(W2 + (size_t)j * 512 + lane * 8);
    const unsigned int wu[4] = {wv.x, wv.y, wv.z, wv.w};
    float s = 0.f;
#pragma unroll
    for (int i = 0; i < 4; ++i) {
      s = fmaf(asf(hu[i] << 16), asf(wu[i] << 16), s);
      s = fmaf(asf(hu[i] & 0xffff0000u), asf(wu[i] & 0xffff0000u), s);
    }
#pragma unroll
    for (int off = 32; off > 0; off >>= 1) s += __shfl_xor(s, off);
    logit[j] = s + bf2f(b2[j]);
  }
  float mx = logit[0];
#pragma unroll
  for (int j = 1; j < 10; ++j) mx = fmaxf(mx, logit[j]);
  float e[10]; float sum = 0.f;
#pragma unroll
  for (int j = 0; j < 10; ++j) { e[j] = __builtin_amdgcn_exp2f(1.442695040888963f * (logit[j] - mx)); sum += e[j]; }
  const float rs = __builtin_amdgcn_rcpf(sum);
  if (lane < 10) {
    float p = e[0];
#pragma unroll
    for (int j = 1; j < 10; ++j) p = (lane == j) ? e[j] : p;
    if (flag[0]) ((float*)out)[row * 10 + lane] = p * rs;
    else         ((unsigned short*)out)[row * 10 + lane] = f2bf(p * rs);
  }
}

// ---------------------------------------------------------------------------
extern "C" void kernel_launch(void* const* d_in, const int* in_sizes, int n_in,
                              void* d_out, int out_size, void* d_ws, size_t ws_size,
                              hipStream_t stream)
{
  (void)in_sizes; (void)n_in; (void)out_size;
  const int* seqs = (const int*)d_in[0];
  const int* lens = (const int*)d_in[1];
  char* ws = (char*)d_ws;

  int* flag = (int*)(ws + OFF_FLAG);
  float* hstate = (float*)(ws + OFF_HST);
  unsigned short* rep  = (unsigned short*)(ws + OFF_REP);
  unsigned short* hid  = (unsigned short*)(ws + OFF_HID);
  unsigned short* WihF = (unsigned short*)(ws + OFF_WIHF);
  unsigned short* WhhF = (unsigned short*)(ws + OFF_WHHF);
  unsigned short* WihB = (unsigned short*)(ws + OFF_WIHB);
  unsigned short* WhhB = (unsigned short*)(ws + OFF_WHHB);
  unsigned short* bihF = (unsigned short*)(ws + OFF_BIHF);
  unsigned short* bhhF = (unsigned short*)(ws + OFF_BHHF);
  unsigned short* bihB = (unsigned short*)(ws + OFF_BIHB);
  unsigned short* bhhB = (unsigned short*)(ws + OFF_BHHB);
  unsigned short* W1C  = (unsigned short*)(ws + OFF_W1);
  unsigned short* b1C  = (unsigned short*)(ws + OFF_B1);
  unsigned short* W2C  = (unsigned short*)(ws + OFF_W2);
  unsigned short* b2C  = (unsigned short*)(ws + OFF_B2);
  unsigned short* embC = (unsigned short*)(ws + OFF_EMB);

  detect<<<1, 256, 0, stream>>>((const unsigned int*)d_in[4], flag);
  Ptrs ps;
  ps.p[0] = d_in[3];  ps.p[1] = d_in[4];  ps.p[2] = d_in[7];  ps.p[3] = d_in[8];
  ps.p[4] = d_in[5];  ps.p[5] = d_in[6];  ps.p[6] = d_in[9];  ps.p[7] = d_in[10];
  ps.p[8] = d_in[11]; ps.p[9] = d_in[12]; ps.p[10] = d_in[13]; ps.p[11] = d_in[14];
  cvt_seg<<<dim3(64, 12), 256, 0, stream>>>(ps, ws, flag);
  cvt_emb<<<2048, 256, 0, stream>>>(d_in[2], embC, flag);

  zerok<<<128, 256, 0, stream>>>((uint4*)hstate, 32768);

  // Tc: ping-pong fp32 gi needs OFF_GI + 4*Tc*786432 bytes
  int Tc = 4;
  const int cands[4] = {32, 16, 8, 4};
  for (int i = 0; i < 4; ++i) {
    if (OFF_GI + 4ull * (size_t)cands[i] * 786432ull <= ws_size) { Tc = cands[i]; break; }
  }
  float* gi0 = (float*)(ws + OFF_GI);
  float* gi1 = gi0 + 2ull * (size_t)Tc * 196608ull;

  // prologue: chunk 0 into gi0
  gi_gemm<<<dim3(6, Tc * 2, 2), 512, 0, stream>>>(seqs, lens, embC, WihF, WihB,
      gi0, gi0 + (size_t)Tc * 196608ull, 0, 512 - Tc);

  const int NC = 512 / Tc;
  for (int c = 0; c < NC; ++c) {
    float* rd = (c & 1) ? gi1 : gi0;
    float* wr = (c & 1) ? gi0 : gi1;
    const int t0f = c * Tc;
    const int t0b = 512 - (c + 1) * Tc;
    const int t0fg = (c + 1) * Tc;
    const int t0bg = 512 - (c + 2) * Tc;
    fused_step<<<32 + 24 * Tc, 512, 0, stream>>>(
        seqs, lens, embC, WihF, WihB, WhhF, WhhB,
        bihF, bhhF, bihB, bhhB, rd, wr, hstate, rep,
        t0f, t0b, t0fg, t0bg, Tc, (c + 1 < NC) ? 1 : 0);
  }
  head1<<<dim3(16, 2), 256, 0, stream>>>(rep, W1C, b1C, hid);
  head2<<<256, 64, 0, stream>>>(hid, W2C, b2C, d_out, flag);
}